// Round 18
// baseline (324.371 us; speedup 1.0000x reference)
//
#include <hip/hip_runtime.h>
#include <hip/hip_bf16.h>

#define TSEQ 4096
#define EMB 768
#define NH 12
#define DH 64
#define BT 8192   // B*T
#define NROWS (24 * TSEQ)  // bh-major partial rows

typedef __attribute__((ext_vector_type(8))) short bf16x8;
typedef __attribute__((ext_vector_type(4))) float f32x4;

#define FENCE() asm volatile("" ::: "memory")

__device__ __forceinline__ f32x4 mfma16(bf16x8 a, bf16x8 b, f32x4 c) {
    return __builtin_amdgcn_mfma_f32_16x16x32_bf16(a, b, c, 0, 0, 0);
}

__device__ __forceinline__ void gload16(const void* g, void* l) {
    __builtin_amdgcn_global_load_lds((const __attribute__((address_space(1))) void*)g,
                                     (__attribute__((address_space(3))) void*)l, 16, 0, 0);
}

// ---------- merged conversion kernel ----------
__global__ __launch_bounds__(256) void conv_all_k(const float* __restrict__ x,
                                                  __hip_bfloat16* __restrict__ xb,
                                                  const float* w0, const float* w1,
                                                  const float* w2, const float* w3,
                                                  __hip_bfloat16* o0, __hip_bfloat16* o1,
                                                  __hip_bfloat16* o2, __hip_bfloat16* o3) {
    __shared__ float tile[32][33];
    int bid = blockIdx.x;
    if (bid < 6144) {
        int i = (bid * 256 + threadIdx.x) * 4;
        float4 v = *(const float4*)(x + i);
        union { unsigned short u[4]; uint2 p; } o;
        __hip_bfloat16 t0 = __float2bfloat16(v.x); o.u[0] = *(unsigned short*)&t0;
        __hip_bfloat16 t1 = __float2bfloat16(v.y); o.u[1] = *(unsigned short*)&t1;
        __hip_bfloat16 t2 = __float2bfloat16(v.z); o.u[2] = *(unsigned short*)&t2;
        __hip_bfloat16 t3 = __float2bfloat16(v.w); o.u[3] = *(unsigned short*)&t3;
        *(uint2*)(xb + i) = o.p;
        return;
    }
    bid -= 6144;
    const int z = bid / 576, rr = bid % 576, by = rr / 24, bx = rr % 24;
    const float* w; __hip_bfloat16* o;
    switch (z) {
        case 0: w = w0; o = o0; break;
        case 1: w = w1; o = o1; break;
        case 2: w = w2; o = o2; break;
        default: w = w3; o = o3; break;
    }
    int tx = threadIdx.x & 31, ty = threadIdx.x >> 5;  // 32 x 8
    int kb = by * 32, nb = bx * 32;
    for (int i = 0; i < 32; i += 8)
        tile[ty + i][tx] = w[(size_t)(kb + ty + i) * EMB + nb + tx];
    __syncthreads();
    for (int i = 0; i < 32; i += 8)
        o[(size_t)(nb + ty + i) * EMB + kb + tx] = __float2bfloat16(tile[tx][ty + i]);
}

// ---------- GEMM body (128x128), one barrier per K-step ----------
__device__ __forceinline__ void gemm_body(const __hip_bfloat16* __restrict__ A,
                                          const __hip_bfloat16* __restrict__ Wt,
                                          const float* __restrict__ bias,
                                          void* __restrict__ outp, int mode, float scale) {
    __shared__ alignas(16) char As[2][8192];
    __shared__ alignas(16) char Bs[2][8192];
    const int m0 = blockIdx.x * 128, n0 = blockIdx.y * 128;
    const int tid = threadIdx.x;
    const int lane = tid & 63, l15 = lane & 15, lg = lane >> 4;
    const int wave = tid >> 6, wm = wave >> 1, wn = wave & 1;
    const int swz = (l15 & 7) << 4;

    int mrow_[2]; int kelem_[2];
#pragma unroll
    for (int c = 0; c < 2; ++c) {
        int p = c * 4096 + tid * 16;
        int lrow = p >> 7, w = p & 127;
        int wp = w ^ ((lrow & 7) << 4);
        mrow_[c] = lrow + ((wp >> 6) & 1) * 64;
        kelem_[c] = (wp & 63) >> 1;
    }

    f32x4 acc[4][4];
    for (int i = 0; i < 4; ++i)
        for (int j = 0; j < 4; ++j) acc[i][j] = (f32x4){0.f, 0.f, 0.f, 0.f};

    auto stage = [&](int buf, int k0) {
#pragma unroll
        for (int c = 0; c < 2; ++c)
            gload16(A + (size_t)(m0 + mrow_[c]) * EMB + k0 + kelem_[c],
                    As[buf] + c * 4096 + wave * 1024);
#pragma unroll
        for (int c = 0; c < 2; ++c)
            gload16(Wt + (size_t)(n0 + mrow_[c]) * EMB + k0 + kelem_[c],
                    Bs[buf] + c * 4096 + wave * 1024);
    };

    stage(0, 0);
    const int NK = EMB / 32;
    for (int ks = 0; ks < NK; ++ks) {
        const int cur = ks & 1;
        asm volatile("s_waitcnt vmcnt(0)" ::: "memory");
        FENCE(); __builtin_amdgcn_s_barrier(); FENCE();
        if (ks + 1 < NK) stage(cur ^ 1, (ks + 1) * 32);
        bf16x8 af[4], bfv[4];
#pragma unroll
        for (int f = 0; f < 4; ++f)
            af[f] = *(const bf16x8*)(As[cur] + (f * 16 + l15) * 128 + ((wm * 64 + lg * 16) ^ swz));
#pragma unroll
        for (int f = 0; f < 4; ++f)
            bfv[f] = *(const bf16x8*)(Bs[cur] + (f * 16 + l15) * 128 + ((wn * 64 + lg * 16) ^ swz));
        __builtin_amdgcn_s_setprio(1);
#pragma unroll
        for (int i = 0; i < 4; ++i)
#pragma unroll
            for (int j = 0; j < 4; ++j)
                acc[i][j] = mfma16(af[i], bfv[j], acc[i][j]);
        __builtin_amdgcn_s_setprio(0);
    }

#pragma unroll
    for (int i = 0; i < 4; ++i) {
#pragma unroll
        for (int j = 0; j < 4; ++j) {
            const int n = n0 + wn * 64 + j * 16 + l15;
            const float bv = bias[n];
            const int mbase = m0 + wm * 64 + i * 16 + lg * 4;
#pragma unroll
            for (int r = 0; r < 4; ++r) {
                const int m = mbase + r;
                const float val = (acc[i][j][r] + bv) * scale;
                if (mode == 2) {
                    ((float*)outp)[(size_t)m * EMB + n] = val;
                } else {
                    const int b = m >> 12, t = m & (TSEQ - 1);
                    const int h = n >> 6, d = n & 63;
                    size_t addr;
                    if (mode == 0) addr = ((size_t)(b * NH + h) * TSEQ + t) * DH + d;
                    else           addr = ((size_t)(b * NH + h) * DH + d) * TSEQ + t;
                    ((__hip_bfloat16*)outp)[addr] = __float2bfloat16(val);
                }
            }
        }
    }
}

__global__ __launch_bounds__(256) void qkv_k(const __hip_bfloat16* __restrict__ xb,
                                             const __hip_bfloat16* __restrict__ wqT,
                                             const __hip_bfloat16* __restrict__ wkT,
                                             const __hip_bfloat16* __restrict__ wvT,
                                             const float* __restrict__ bq,
                                             const float* __restrict__ bk,
                                             const float* __restrict__ bv,
                                             __hip_bfloat16* __restrict__ qo,
                                             __hip_bfloat16* __restrict__ ko,
                                             __hip_bfloat16* __restrict__ vo) {
    const __hip_bfloat16* Wt; const float* bias; void* o; int mode; float scale;
    const float cq = 0.125f * 1.44269504089f;  // softmax scale * log2(e), folded into Q
    switch (blockIdx.z) {
        case 0:  Wt = wqT; bias = bq; o = qo; mode = 0; scale = cq;  break;
        case 1:  Wt = wkT; bias = bk; o = ko; mode = 0; scale = 1.f; break;
        default: Wt = wvT; bias = bv; o = vo; mode = 1; scale = 1.f; break;
    }
    gemm_body(xb, Wt, bias, o, mode, scale);
}

// ---------- oproj, 64x128 tile, one barrier per K-step ----------
__global__ __launch_bounds__(256) void oproj64_k(const __hip_bfloat16* __restrict__ A,
                                                 const __hip_bfloat16* __restrict__ Wt,
                                                 const float* __restrict__ bias,
                                                 float* __restrict__ out) {
    __shared__ alignas(16) char As[2][4096];
    __shared__ alignas(16) char Bs[2][8192];
    const int m0 = blockIdx.x * 64, n0 = blockIdx.y * 128;
    const int tid = threadIdx.x;
    const int lane = tid & 63, l15 = lane & 15, lg = lane >> 4;
    const int wave = tid >> 6, wm = wave >> 1, wn = wave & 1;
    const int swz = (l15 & 7) << 4;

    int amrow, akelem;
    {
        int p = tid * 16;
        int lrow = p >> 7, w = p & 127;
        int wp = w ^ ((lrow & 7) << 4);
        amrow = lrow + ((wp >> 6) & 1) * 32;
        akelem = (wp & 63) >> 1;
    }
    int bnrow[2], bkelem[2];
#pragma unroll
    for (int c = 0; c < 2; ++c) {
        int p = c * 4096 + tid * 16;
        int lrow = p >> 7, w = p & 127;
        int wp = w ^ ((lrow & 7) << 4);
        bnrow[c] = lrow + ((wp >> 6) & 1) * 64;
        bkelem[c] = (wp & 63) >> 1;
    }

    f32x4 acc[2][4];
    for (int i = 0; i < 2; ++i)
        for (int j = 0; j < 4; ++j) acc[i][j] = (f32x4){0.f, 0.f, 0.f, 0.f};

    auto stage = [&](int buf, int k0) {
        gload16(A + (size_t)(m0 + amrow) * EMB + k0 + akelem,
                As[buf] + wave * 1024);
#pragma unroll
        for (int c = 0; c < 2; ++c)
            gload16(Wt + (size_t)(n0 + bnrow[c]) * EMB + k0 + bkelem[c],
                    Bs[buf] + c * 4096 + wave * 1024);
    };

    stage(0, 0);
    const int NK = EMB / 32;
    for (int ks = 0; ks < NK; ++ks) {
        const int cur = ks & 1;
        asm volatile("s_waitcnt vmcnt(0)" ::: "memory");
        FENCE(); __builtin_amdgcn_s_barrier(); FENCE();
        if (ks + 1 < NK) stage(cur ^ 1, (ks + 1) * 32);
        bf16x8 af[2], bfv[4];
#pragma unroll
        for (int f = 0; f < 2; ++f)
            af[f] = *(const bf16x8*)(As[cur] + (f * 16 + l15) * 128 + ((wm * 64 + lg * 16) ^ swz));
#pragma unroll
        for (int f = 0; f < 4; ++f)
            bfv[f] = *(const bf16x8*)(Bs[cur] + (f * 16 + l15) * 128 + ((wn * 64 + lg * 16) ^ swz));
        __builtin_amdgcn_s_setprio(1);
#pragma unroll
        for (int i = 0; i < 2; ++i)
#pragma unroll
            for (int j = 0; j < 4; ++j)
                acc[i][j] = mfma16(af[i], bfv[j], acc[i][j]);
        __builtin_amdgcn_s_setprio(0);
    }

#pragma unroll
    for (int i = 0; i < 2; ++i) {
#pragma unroll
        for (int j = 0; j < 4; ++j) {
            const int n = n0 + wn * 64 + j * 16 + l15;
            const float bv = bias[n];
            const int mbase = m0 + wm * 32 + i * 16 + lg * 4;
#pragma unroll
            for (int r = 0; r < 4; ++r)
                out[(size_t)(mbase + r) * EMB + n] = acc[i][j][r] + bv;
        }
    }
}

// ---------- flash attention, FIXED-M softmax, PARITY-SPLIT ----------
// r15 chassis + split-K over s-blocks: each (pair) is handled by TWO blocks
// (parity 0 = even s-blocks, parity 1 = odd). Fixed-M makes partials purely
// additive (O = O0+O1, l = l0+l1) — no max merge. Grid 1536; K/V single-
// buffered (LDS 32 KB -> 5 blocks/CU resident = 20 waves/CU, up from 12;
// the kernel was occupancy-limited: no pipe >52% at 12 waves).
// Per event: vmcnt(0);bar; kf reads; QKSM(hi/lo); vf reads; lgkm(0); bar;
// STAGE(next) overlapping PVU (PVU needs only registers + pbuf).
__global__ __launch_bounds__(256, 5) void attn_k(const __hip_bfloat16* __restrict__ qb,
                                                 const __hip_bfloat16* __restrict__ kb,
                                                 const __hip_bfloat16* __restrict__ vt,
                                                 __hip_bfloat16* __restrict__ opart,
                                                 float* __restrict__ lpart) {
    __shared__ alignas(16) char Ks[8192];
    __shared__ alignas(16) char Vs[8192];
    __shared__ alignas(16) char pbuf[4][4096];  // per-wave: hi half + lo half
    const int lane = threadIdx.x & 63, l15 = lane & 15, lg = lane >> 4;
    const int wave = threadIdx.x >> 6;
    const int bid = blockIdx.x;
    const int xcd = bid & 7, slot = bid >> 3;          // slot 0..191
    const int pair = slot & 31;
    const int parity = (slot >> 5) & 1;
    const int hgrp = slot >> 6;                        // 0..2
    const int bh = xcd + hgrp * 8;                     // head-clustered XCD mapping
    const __hip_bfloat16* Qh = qb + (size_t)bh * TSEQ * DH;
    const __hip_bfloat16* Kh = kb + (size_t)bh * TSEQ * DH;
    const __hip_bfloat16* Vh = vt + (size_t)bh * DH * TSEQ;
    char* Pb = pbuf[wave];
    const int swz = (l15 & 7) << 4;
    const float M0 = 12.0f;  // fixed softmax reference (log2 domain)

    bf16x8 ones8;
#pragma unroll
    for (int j = 0; j < 8; ++j) ones8[j] = (short)0x3F80;  // bf16 1.0

    // hoisted loop-invariant LDS addresses
    unsigned ka[8];
#pragma unroll
    for (int st = 0; st < 4; ++st)
#pragma unroll
        for (int ks = 0; ks < 2; ++ks)
            ka[st * 2 + ks] = (unsigned)((st * 16 + l15) * 128 + ((ks * 64 + lg * 16) ^ swz));
    char* pwh[4]; char* prh[2]; char* pwl[4]; char* prl[2];
#pragma unroll
    for (int st = 0; st < 4; ++st) {
        pwh[st] = Pb + l15 * 128 + ((st * 32 + lg * 8) ^ swz);
        pwl[st] = pwh[st] + 2048;
    }
#pragma unroll
    for (int ks = 0; ks < 2; ++ks) {
        prh[ks] = Pb + l15 * 128 + ((ks * 64 + lg * 16) ^ swz);
        prl[ks] = prh[ks] + 2048;
    }
    const int dthr = wave * 16 + l15 - lg * 4;  // mask when st*16 + r > dthr

    // staging geometry: chunk c: linear p = c*4096 + wave*1024 + lane*16
    int r_[2], wp_[2];
#pragma unroll
    for (int c = 0; c < 2; ++c) {
        int p = c * 4096 + wave * 1024 + lane * 16;
        int r = p >> 7, w = p & 127;
        r_[c] = r;
        wp_[c] = (w ^ ((r & 7) << 4)) >> 1;
    }

    const int lo = pair, hi = 63 - pair;
    const int q0l = lo * 64 + wave * 16;
    const int q0h = hi * 64 + wave * 16;
    const int nsb = hi + 1;

    // Q fragments for both tiles
    bf16x8 qh0 = *(const bf16x8*)(Qh + (size_t)(q0h + l15) * DH + lg * 8);
    bf16x8 qh1 = *(const bf16x8*)(Qh + (size_t)(q0h + l15) * DH + 32 + lg * 8);
    bf16x8 ql0 = *(const bf16x8*)(Qh + (size_t)(q0l + l15) * DH + lg * 8);
    bf16x8 ql1 = *(const bf16x8*)(Qh + (size_t)(q0l + l15) * DH + 32 + lg * 8);

    f32x4 oh[4], ol[4];
#pragma unroll
    for (int dt = 0; dt < 4; ++dt) { oh[dt] = (f32x4){0.f,0.f,0.f,0.f}; ol[dt] = (f32x4){0.f,0.f,0.f,0.f}; }
    f32x4 lh = (f32x4){0.f,0.f,0.f,0.f}, ll = (f32x4){0.f,0.f,0.f,0.f};

    // global staging pointers, offset to this parity's first s-block
    const char* kg0 = (const char*)(Kh + (size_t)r_[0] * DH + wp_[0]) + parity * 8192;
    const char* kg1 = (const char*)(Kh + (size_t)r_[1] * DH + wp_[1]) + parity * 8192;
    const char* vg0 = (const char*)(Vh + (size_t)r_[0] * TSEQ + wp_[0]) + parity * 128;
    const char* vg1 = (const char*)(Vh + (size_t)r_[1] * TSEQ + wp_[1]) + parity * 128;

#define STAGE() do {                                                             \
    gload16(kg0, Ks + wave * 1024);                                              \
    gload16(kg1, Ks + 4096 + wave * 1024);                                       \
    gload16(vg0, Vs + wave * 1024);                                              \
    gload16(vg1, Vs + 4096 + wave * 1024);                                       \
    kg0 += 16384; kg1 += 16384; vg0 += 256; vg1 += 256;                          \
} while (0)

// QK^T + fixed-M exp2 + P-pack + P-write (no max tracking, no cross-lane ops)
#define QKSM(KF, Q0, Q1, MASKB, PW) do {                                         \
    f32x4 sa[4];                                                                 \
    __builtin_amdgcn_s_setprio(1);                                               \
    _Pragma("unroll")                                                            \
    for (int st = 0; st < 4; ++st) {                                             \
        f32x4 z = (f32x4){0.f, 0.f, 0.f, 0.f};                                   \
        z = mfma16(KF[st * 2 + 0], Q0, z);                                       \
        z = mfma16(KF[st * 2 + 1], Q1, z);                                       \
        sa[st] = z;                                                              \
    }                                                                            \
    __builtin_amdgcn_s_setprio(0);                                               \
    if (MASKB) {                                                                 \
        _Pragma("unroll")                                                        \
        for (int st = 0; st < 4; ++st)                                           \
            _Pragma("unroll")                                                    \
            for (int r = 0; r < 4; ++r)                                          \
                if (st * 16 + r > dthr) sa[st][r] = -INFINITY;                   \
    }                                                                            \
    _Pragma("unroll")                                                            \
    for (int st = 0; st < 4; ++st) {                                             \
        const float e0 = exp2f(sa[st][0] - M0);                                  \
        const float e1 = exp2f(sa[st][1] - M0);                                  \
        const float e2 = exp2f(sa[st][2] - M0);                                  \
        const float e3 = exp2f(sa[st][3] - M0);                                  \
        uint2 pkv;                                                               \
        asm("v_cvt_pk_bf16_f32 %0, %1, %2" : "=v"(pkv.x) : "v"(e0), "v"(e1));    \
        asm("v_cvt_pk_bf16_f32 %0, %1, %2" : "=v"(pkv.y) : "v"(e2), "v"(e3));    \
        *(uint2*)PW[st] = pkv;                                                   \
    }                                                                            \
} while (0)

// P read + denominator + PV MFMAs, using pre-loaded V fragments
#define PVU(VF, OV, LA, PR) do {                                                 \
    bf16x8 pf0 = *(const bf16x8*)PR[0];                                          \
    bf16x8 pf1 = *(const bf16x8*)PR[1];                                          \
    __builtin_amdgcn_s_setprio(1);                                               \
    LA = mfma16(pf0, ones8, LA);                                                 \
    LA = mfma16(pf1, ones8, LA);                                                 \
    _Pragma("unroll")                                                            \
    for (int dt = 0; dt < 4; ++dt)                                               \
        OV[dt] = mfma16(pf0, VF[dt * 2 + 0], OV[dt]);                            \
    _Pragma("unroll")                                                            \
    for (int dt = 0; dt < 4; ++dt)                                               \
        OV[dt] = mfma16(pf1, VF[dt * 2 + 1], OV[dt]);                            \
    __builtin_amdgcn_s_setprio(0);                                               \
} while (0)

    STAGE();  // first event's K/V
    for (int sb = parity; sb < nsb; sb += 2) {
        const bool loact = (sb <= lo);
        asm volatile("s_waitcnt vmcnt(0)" ::: "memory");
        FENCE(); __builtin_amdgcn_s_barrier(); FENCE();
        bf16x8 kf[8];
#pragma unroll
        for (int i = 0; i < 8; ++i) kf[i] = *(const bf16x8*)(Ks + ka[i]);
        QKSM(kf, qh0, qh1, (sb == hi), pwh);
        if (loact) QKSM(kf, ql0, ql1, (sb == lo), pwl);
        bf16x8 vf[8];
#pragma unroll
        for (int i = 0; i < 8; ++i) vf[i] = *(const bf16x8*)(Vs + ka[i]);
        asm volatile("s_waitcnt lgkmcnt(0)" ::: "memory");
        FENCE(); __builtin_amdgcn_s_barrier(); FENCE();  // all waves done with K/V LDS
        if (sb + 2 < nsb) STAGE();                        // overlaps PV below
        PVU(vf, oh, lh, prh);
        if (loact) PVU(vf, ol, ll, prl);
    }

#undef PVU
#undef QKSM
#undef STAGE

    // ---- write partials (bf16 O, fp32 l); additive across parities ----
    const size_t prow = ((size_t)parity * 24 + bh) * TSEQ;
    {
#pragma unroll
        for (int r = 0; r < 4; ++r) {
            const size_t base = (prow + q0h + lg * 4 + r) * DH;
#pragma unroll
            for (int dt = 0; dt < 4; ++dt)
                opart[base + dt * 16 + l15] = __float2bfloat16(oh[dt][r]);
        }
        if (l15 == 0) {
#pragma unroll
            for (int r = 0; r < 4; ++r) lpart[prow + q0h + lg * 4 + r] = lh[r];
        }
    }
    {
#pragma unroll
        for (int r = 0; r < 4; ++r) {
            const size_t base = (prow + q0l + lg * 4 + r) * DH;
#pragma unroll
            for (int dt = 0; dt < 4; ++dt)
                opart[base + dt * 16 + l15] = __float2bfloat16(ol[dt][r]);
        }
        if (l15 == 0) {
#pragma unroll
            for (int r = 0; r < 4; ++r) lpart[prow + q0l + lg * 4 + r] = ll[r];
        }
    }
}

// ---------- combine: ab = (O0 + O1) / (l0 + l1), bf16 ----------
__global__ __launch_bounds__(256) void comb_k(const __hip_bfloat16* __restrict__ opart,
                                              const float* __restrict__ lpart,
                                              __hip_bfloat16* __restrict__ ab) {
    const int idx = blockIdx.x * 256 + threadIdx.x;
    const int row = idx >> 3;                // bh*4096 + qrow
    const int d0 = (idx & 7) * 8;
    const int bh = row >> 12, qrow = row & 4095;
    const int b_ = bh / NH, h = bh % NH;
    bf16x8 a0 = *(const bf16x8*)(opart + (size_t)row * DH + d0);
    bf16x8 a1 = *(const bf16x8*)(opart + ((size_t)NROWS + row) * DH + d0);
    const float linv = 1.0f / (lpart[row] + lpart[NROWS + row]);
    union { unsigned short u[8]; uint4 v; } o;
#pragma unroll
    for (int j = 0; j < 8; ++j) {
        const float v0 = __uint_as_float(((unsigned)(unsigned short)a0[j]) << 16);
        const float v1 = __uint_as_float(((unsigned)(unsigned short)a1[j]) << 16);
        __hip_bfloat16 hb = __float2bfloat16((v0 + v1) * linv);
        o.u[j] = *(unsigned short*)&hb;
    }
    *(uint4*)(ab + ((size_t)(b_ * TSEQ + qrow)) * EMB + h * DH + d0) = o.v;
}

extern "C" void kernel_launch(void* const* d_in, const int* in_sizes, int n_in,
                              void* d_out, int out_size, void* d_ws, size_t ws_size,
                              hipStream_t stream) {
    (void)in_sizes; (void)n_in; (void)out_size; (void)ws_size;
    const float* x  = (const float*)d_in[0];
    const float* wq = (const float*)d_in[1];
    const float* bq = (const float*)d_in[2];
    const float* wk = (const float*)d_in[3];
    const float* bk = (const float*)d_in[4];
    const float* wv = (const float*)d_in[5];
    const float* bv = (const float*)d_in[6];
    const float* wo = (const float*)d_in[7];
    const float* bo = (const float*)d_in[8];
    float* out = (float*)d_out;

    char* ws = (char*)d_ws;
    size_t off = 0;
    auto alloc = [&](size_t bytes) {
        char* p = ws + off;
        off += (bytes + 255) & ~(size_t)255;
        return p;
    };
    __hip_bfloat16* xb   = (__hip_bfloat16*)alloc((size_t)BT * EMB * 2);
    __hip_bfloat16* qbf  = (__hip_bfloat16*)alloc((size_t)BT * EMB * 2);
    __hip_bfloat16* kbf  = (__hip_bfloat16*)alloc((size_t)BT * EMB * 2);
    __hip_bfloat16* vtb  = (__hip_bfloat16*)alloc((size_t)BT * EMB * 2);
    __hip_bfloat16* abf  = (__hip_bfloat16*)alloc((size_t)BT * EMB * 2);
    __hip_bfloat16* wqT  = (__hip_bfloat16*)alloc((size_t)EMB * EMB * 2);
    __hip_bfloat16* wkT  = (__hip_bfloat16*)alloc((size_t)EMB * EMB * 2);
    __hip_bfloat16* wvT  = (__hip_bfloat16*)alloc((size_t)EMB * EMB * 2);
    __hip_bfloat16* woT  = (__hip_bfloat16*)alloc((size_t)EMB * EMB * 2);
    __hip_bfloat16* opart = (__hip_bfloat16*)alloc((size_t)2 * NROWS * DH * 2);
    float*          lpart = (float*)alloc((size_t)2 * NROWS * 4);

    conv_all_k<<<6144 + 2304, 256, 0, stream>>>(x, xb, wq, wk, wv, wo, wqT, wkT, wvT, woT);
    qkv_k<<<dim3(64, 6, 3), 256, 0, stream>>>(xb, wqT, wkT, wvT, bq, bk, bv, qbf, kbf, vtb);
    attn_k<<<1536, 256, 0, stream>>>(qbf, kbf, vtb, opart, lpart);
    comb_k<<<NROWS * 8 / 256, 256, 0, stream>>>(opart, lpart, abf);
    oproj64_k<<<dim3(128, 6), 256, 0, stream>>>(abf, woT, bo, out);
}

// Round 19
// 183.036 us; speedup vs baseline: 1.7722x; 1.7722x over previous
//
#include <hip/hip_runtime.h>
#include <hip/hip_bf16.h>

#define TSEQ 4096
#define EMB 768
#define NH 12
#define DH 64
#define BT 8192   // B*T
#define NROWS (24 * TSEQ)  // bh-major partial rows

typedef __attribute__((ext_vector_type(8))) short bf16x8;
typedef __attribute__((ext_vector_type(4))) float f32x4;

#define FENCE() asm volatile("" ::: "memory")

__device__ __forceinline__ f32x4 mfma16(bf16x8 a, bf16x8 b, f32x4 c) {
    return __builtin_amdgcn_mfma_f32_16x16x32_bf16(a, b, c, 0, 0, 0);
}

__device__ __forceinline__ void gload16(const void* g, void* l) {
    __builtin_amdgcn_global_load_lds((const __attribute__((address_space(1))) void*)g,
                                     (__attribute__((address_space(3))) void*)l, 16, 0, 0);
}

// ---------- merged conversion kernel ----------
__global__ __launch_bounds__(256) void conv_all_k(const float* __restrict__ x,
                                                  __hip_bfloat16* __restrict__ xb,
                                                  const float* w0, const float* w1,
                                                  const float* w2, const float* w3,
                                                  __hip_bfloat16* o0, __hip_bfloat16* o1,
                                                  __hip_bfloat16* o2, __hip_bfloat16* o3) {
    __shared__ float tile[32][33];
    int bid = blockIdx.x;
    if (bid < 6144) {
        int i = (bid * 256 + threadIdx.x) * 4;
        float4 v = *(const float4*)(x + i);
        union { unsigned short u[4]; uint2 p; } o;
        __hip_bfloat16 t0 = __float2bfloat16(v.x); o.u[0] = *(unsigned short*)&t0;
        __hip_bfloat16 t1 = __float2bfloat16(v.y); o.u[1] = *(unsigned short*)&t1;
        __hip_bfloat16 t2 = __float2bfloat16(v.z); o.u[2] = *(unsigned short*)&t2;
        __hip_bfloat16 t3 = __float2bfloat16(v.w); o.u[3] = *(unsigned short*)&t3;
        *(uint2*)(xb + i) = o.p;
        return;
    }
    bid -= 6144;
    const int z = bid / 576, rr = bid % 576, by = rr / 24, bx = rr % 24;
    const float* w; __hip_bfloat16* o;
    switch (z) {
        case 0: w = w0; o = o0; break;
        case 1: w = w1; o = o1; break;
        case 2: w = w2; o = o2; break;
        default: w = w3; o = o3; break;
    }
    int tx = threadIdx.x & 31, ty = threadIdx.x >> 5;  // 32 x 8
    int kb = by * 32, nb = bx * 32;
    for (int i = 0; i < 32; i += 8)
        tile[ty + i][tx] = w[(size_t)(kb + ty + i) * EMB + nb + tx];
    __syncthreads();
    for (int i = 0; i < 32; i += 8)
        o[(size_t)(nb + ty + i) * EMB + kb + tx] = __float2bfloat16(tile[tx][ty + i]);
}

// ---------- GEMM body (128x128), one barrier per K-step ----------
__device__ __forceinline__ void gemm_body(const __hip_bfloat16* __restrict__ A,
                                          const __hip_bfloat16* __restrict__ Wt,
                                          const float* __restrict__ bias,
                                          void* __restrict__ outp, int mode, float scale) {
    __shared__ alignas(16) char As[2][8192];
    __shared__ alignas(16) char Bs[2][8192];
    const int m0 = blockIdx.x * 128, n0 = blockIdx.y * 128;
    const int tid = threadIdx.x;
    const int lane = tid & 63, l15 = lane & 15, lg = lane >> 4;
    const int wave = tid >> 6, wm = wave >> 1, wn = wave & 1;
    const int swz = (l15 & 7) << 4;

    int mrow_[2]; int kelem_[2];
#pragma unroll
    for (int c = 0; c < 2; ++c) {
        int p = c * 4096 + tid * 16;
        int lrow = p >> 7, w = p & 127;
        int wp = w ^ ((lrow & 7) << 4);
        mrow_[c] = lrow + ((wp >> 6) & 1) * 64;
        kelem_[c] = (wp & 63) >> 1;
    }

    f32x4 acc[4][4];
    for (int i = 0; i < 4; ++i)
        for (int j = 0; j < 4; ++j) acc[i][j] = (f32x4){0.f, 0.f, 0.f, 0.f};

    auto stage = [&](int buf, int k0) {
#pragma unroll
        for (int c = 0; c < 2; ++c)
            gload16(A + (size_t)(m0 + mrow_[c]) * EMB + k0 + kelem_[c],
                    As[buf] + c * 4096 + wave * 1024);
#pragma unroll
        for (int c = 0; c < 2; ++c)
            gload16(Wt + (size_t)(n0 + mrow_[c]) * EMB + k0 + kelem_[c],
                    Bs[buf] + c * 4096 + wave * 1024);
    };

    stage(0, 0);
    const int NK = EMB / 32;
    for (int ks = 0; ks < NK; ++ks) {
        const int cur = ks & 1;
        asm volatile("s_waitcnt vmcnt(0)" ::: "memory");
        FENCE(); __builtin_amdgcn_s_barrier(); FENCE();
        if (ks + 1 < NK) stage(cur ^ 1, (ks + 1) * 32);
        bf16x8 af[4], bfv[4];
#pragma unroll
        for (int f = 0; f < 4; ++f)
            af[f] = *(const bf16x8*)(As[cur] + (f * 16 + l15) * 128 + ((wm * 64 + lg * 16) ^ swz));
#pragma unroll
        for (int f = 0; f < 4; ++f)
            bfv[f] = *(const bf16x8*)(Bs[cur] + (f * 16 + l15) * 128 + ((wn * 64 + lg * 16) ^ swz));
        __builtin_amdgcn_s_setprio(1);
#pragma unroll
        for (int i = 0; i < 4; ++i)
#pragma unroll
            for (int j = 0; j < 4; ++j)
                acc[i][j] = mfma16(af[i], bfv[j], acc[i][j]);
        __builtin_amdgcn_s_setprio(0);
    }

#pragma unroll
    for (int i = 0; i < 4; ++i) {
#pragma unroll
        for (int j = 0; j < 4; ++j) {
            const int n = n0 + wn * 64 + j * 16 + l15;
            const float bv = bias[n];
            const int mbase = m0 + wm * 64 + i * 16 + lg * 4;
#pragma unroll
            for (int r = 0; r < 4; ++r) {
                const int m = mbase + r;
                const float val = (acc[i][j][r] + bv) * scale;
                if (mode == 2) {
                    ((float*)outp)[(size_t)m * EMB + n] = val;
                } else {
                    const int b = m >> 12, t = m & (TSEQ - 1);
                    const int h = n >> 6, d = n & 63;
                    size_t addr;
                    if (mode == 0) addr = ((size_t)(b * NH + h) * TSEQ + t) * DH + d;
                    else           addr = ((size_t)(b * NH + h) * DH + d) * TSEQ + t;
                    ((__hip_bfloat16*)outp)[addr] = __float2bfloat16(val);
                }
            }
        }
    }
}

__global__ __launch_bounds__(256) void qkv_k(const __hip_bfloat16* __restrict__ xb,
                                             const __hip_bfloat16* __restrict__ wqT,
                                             const __hip_bfloat16* __restrict__ wkT,
                                             const __hip_bfloat16* __restrict__ wvT,
                                             const float* __restrict__ bq,
                                             const float* __restrict__ bk,
                                             const float* __restrict__ bv,
                                             __hip_bfloat16* __restrict__ qo,
                                             __hip_bfloat16* __restrict__ ko,
                                             __hip_bfloat16* __restrict__ vo) {
    const __hip_bfloat16* Wt; const float* bias; void* o; int mode; float scale;
    const float cq = 0.125f * 1.44269504089f;  // softmax scale * log2(e), folded into Q
    switch (blockIdx.z) {
        case 0:  Wt = wqT; bias = bq; o = qo; mode = 0; scale = cq;  break;
        case 1:  Wt = wkT; bias = bk; o = ko; mode = 0; scale = 1.f; break;
        default: Wt = wvT; bias = bv; o = vo; mode = 1; scale = 1.f; break;
    }
    gemm_body(xb, Wt, bias, o, mode, scale);
}

// ---------- oproj, 64x128 tile, one barrier per K-step ----------
__global__ __launch_bounds__(256) void oproj64_k(const __hip_bfloat16* __restrict__ A,
                                                 const __hip_bfloat16* __restrict__ Wt,
                                                 const float* __restrict__ bias,
                                                 float* __restrict__ out) {
    __shared__ alignas(16) char As[2][4096];
    __shared__ alignas(16) char Bs[2][8192];
    const int m0 = blockIdx.x * 64, n0 = blockIdx.y * 128;
    const int tid = threadIdx.x;
    const int lane = tid & 63, l15 = lane & 15, lg = lane >> 4;
    const int wave = tid >> 6, wm = wave >> 1, wn = wave & 1;
    const int swz = (l15 & 7) << 4;

    int amrow, akelem;
    {
        int p = tid * 16;
        int lrow = p >> 7, w = p & 127;
        int wp = w ^ ((lrow & 7) << 4);
        amrow = lrow + ((wp >> 6) & 1) * 32;
        akelem = (wp & 63) >> 1;
    }
    int bnrow[2], bkelem[2];
#pragma unroll
    for (int c = 0; c < 2; ++c) {
        int p = c * 4096 + tid * 16;
        int lrow = p >> 7, w = p & 127;
        int wp = w ^ ((lrow & 7) << 4);
        bnrow[c] = lrow + ((wp >> 6) & 1) * 64;
        bkelem[c] = (wp & 63) >> 1;
    }

    f32x4 acc[2][4];
    for (int i = 0; i < 2; ++i)
        for (int j = 0; j < 4; ++j) acc[i][j] = (f32x4){0.f, 0.f, 0.f, 0.f};

    auto stage = [&](int buf, int k0) {
        gload16(A + (size_t)(m0 + amrow) * EMB + k0 + akelem,
                As[buf] + wave * 1024);
#pragma unroll
        for (int c = 0; c < 2; ++c)
            gload16(Wt + (size_t)(n0 + bnrow[c]) * EMB + k0 + bkelem[c],
                    Bs[buf] + c * 4096 + wave * 1024);
    };

    stage(0, 0);
    const int NK = EMB / 32;
    for (int ks = 0; ks < NK; ++ks) {
        const int cur = ks & 1;
        asm volatile("s_waitcnt vmcnt(0)" ::: "memory");
        FENCE(); __builtin_amdgcn_s_barrier(); FENCE();
        if (ks + 1 < NK) stage(cur ^ 1, (ks + 1) * 32);
        bf16x8 af[2], bfv[4];
#pragma unroll
        for (int f = 0; f < 2; ++f)
            af[f] = *(const bf16x8*)(As[cur] + (f * 16 + l15) * 128 + ((wm * 64 + lg * 16) ^ swz));
#pragma unroll
        for (int f = 0; f < 4; ++f)
            bfv[f] = *(const bf16x8*)(Bs[cur] + (f * 16 + l15) * 128 + ((wn * 64 + lg * 16) ^ swz));
        __builtin_amdgcn_s_setprio(1);
#pragma unroll
        for (int i = 0; i < 2; ++i)
#pragma unroll
            for (int j = 0; j < 4; ++j)
                acc[i][j] = mfma16(af[i], bfv[j], acc[i][j]);
        __builtin_amdgcn_s_setprio(0);
    }

#pragma unroll
    for (int i = 0; i < 2; ++i) {
#pragma unroll
        for (int j = 0; j < 4; ++j) {
            const int n = n0 + wn * 64 + j * 16 + l15;
            const float bv = bias[n];
            const int mbase = m0 + wm * 32 + i * 16 + lg * 4;
#pragma unroll
            for (int r = 0; r < 4; ++r)
                out[(size_t)(mbase + r) * EMB + n] = acc[i][j][r] + bv;
        }
    }
}

// ---------- flash attention, FIXED-M softmax, PARITY-SPLIT ----------
// r18 structure verbatim (correctness-proven) with launch_bounds relaxed
// 5 -> 3. r18's (256,5) forced VGPR to 48 (needs ~110) -> 427 MB scratch
// spill, 248 us. At (256,3) cap=170, natural allocation ~76-100 VGPR
// (r14 measured 76 for this register content) -> occupancy becomes
// min(LDS 160/32=5, 512/VGPR) ~ 5 blocks/CU = 20 waves, no spill.
__global__ __launch_bounds__(256, 3) void attn_k(const __hip_bfloat16* __restrict__ qb,
                                                 const __hip_bfloat16* __restrict__ kb,
                                                 const __hip_bfloat16* __restrict__ vt,
                                                 __hip_bfloat16* __restrict__ opart,
                                                 float* __restrict__ lpart) {
    __shared__ alignas(16) char Ks[8192];
    __shared__ alignas(16) char Vs[8192];
    __shared__ alignas(16) char pbuf[4][4096];  // per-wave: hi half + lo half
    const int lane = threadIdx.x & 63, l15 = lane & 15, lg = lane >> 4;
    const int wave = threadIdx.x >> 6;
    const int bid = blockIdx.x;
    const int xcd = bid & 7, slot = bid >> 3;          // slot 0..191
    const int pair = slot & 31;
    const int parity = (slot >> 5) & 1;
    const int hgrp = slot >> 6;                        // 0..2
    const int bh = xcd + hgrp * 8;                     // head-clustered XCD mapping
    const __hip_bfloat16* Qh = qb + (size_t)bh * TSEQ * DH;
    const __hip_bfloat16* Kh = kb + (size_t)bh * TSEQ * DH;
    const __hip_bfloat16* Vh = vt + (size_t)bh * DH * TSEQ;
    char* Pb = pbuf[wave];
    const int swz = (l15 & 7) << 4;
    const float M0 = 12.0f;  // fixed softmax reference (log2 domain)

    bf16x8 ones8;
#pragma unroll
    for (int j = 0; j < 8; ++j) ones8[j] = (short)0x3F80;  // bf16 1.0

    // hoisted loop-invariant LDS addresses
    unsigned ka[8];
#pragma unroll
    for (int st = 0; st < 4; ++st)
#pragma unroll
        for (int ks = 0; ks < 2; ++ks)
            ka[st * 2 + ks] = (unsigned)((st * 16 + l15) * 128 + ((ks * 64 + lg * 16) ^ swz));
    char* pwh[4]; char* prh[2]; char* pwl[4]; char* prl[2];
#pragma unroll
    for (int st = 0; st < 4; ++st) {
        pwh[st] = Pb + l15 * 128 + ((st * 32 + lg * 8) ^ swz);
        pwl[st] = pwh[st] + 2048;
    }
#pragma unroll
    for (int ks = 0; ks < 2; ++ks) {
        prh[ks] = Pb + l15 * 128 + ((ks * 64 + lg * 16) ^ swz);
        prl[ks] = prh[ks] + 2048;
    }
    const int dthr = wave * 16 + l15 - lg * 4;  // mask when st*16 + r > dthr

    // staging geometry: chunk c: linear p = c*4096 + wave*1024 + lane*16
    int r_[2], wp_[2];
#pragma unroll
    for (int c = 0; c < 2; ++c) {
        int p = c * 4096 + wave * 1024 + lane * 16;
        int r = p >> 7, w = p & 127;
        r_[c] = r;
        wp_[c] = (w ^ ((r & 7) << 4)) >> 1;
    }

    const int lo = pair, hi = 63 - pair;
    const int q0l = lo * 64 + wave * 16;
    const int q0h = hi * 64 + wave * 16;
    const int nsb = hi + 1;

    // Q fragments for both tiles
    bf16x8 qh0 = *(const bf16x8*)(Qh + (size_t)(q0h + l15) * DH + lg * 8);
    bf16x8 qh1 = *(const bf16x8*)(Qh + (size_t)(q0h + l15) * DH + 32 + lg * 8);
    bf16x8 ql0 = *(const bf16x8*)(Qh + (size_t)(q0l + l15) * DH + lg * 8);
    bf16x8 ql1 = *(const bf16x8*)(Qh + (size_t)(q0l + l15) * DH + 32 + lg * 8);

    f32x4 oh[4], ol[4];
#pragma unroll
    for (int dt = 0; dt < 4; ++dt) { oh[dt] = (f32x4){0.f,0.f,0.f,0.f}; ol[dt] = (f32x4){0.f,0.f,0.f,0.f}; }
    f32x4 lh = (f32x4){0.f,0.f,0.f,0.f}, ll = (f32x4){0.f,0.f,0.f,0.f};

    // global staging pointers, offset to this parity's first s-block
    const char* kg0 = (const char*)(Kh + (size_t)r_[0] * DH + wp_[0]) + parity * 8192;
    const char* kg1 = (const char*)(Kh + (size_t)r_[1] * DH + wp_[1]) + parity * 8192;
    const char* vg0 = (const char*)(Vh + (size_t)r_[0] * TSEQ + wp_[0]) + parity * 128;
    const char* vg1 = (const char*)(Vh + (size_t)r_[1] * TSEQ + wp_[1]) + parity * 128;

#define STAGE() do {                                                             \
    gload16(kg0, Ks + wave * 1024);                                              \
    gload16(kg1, Ks + 4096 + wave * 1024);                                       \
    gload16(vg0, Vs + wave * 1024);                                              \
    gload16(vg1, Vs + 4096 + wave * 1024);                                       \
    kg0 += 16384; kg1 += 16384; vg0 += 256; vg1 += 256;                          \
} while (0)

// QK^T + fixed-M exp2 + P-pack + P-write (no max tracking, no cross-lane ops)
#define QKSM(KF, Q0, Q1, MASKB, PW) do {                                         \
    f32x4 sa[4];                                                                 \
    __builtin_amdgcn_s_setprio(1);                                               \
    _Pragma("unroll")                                                            \
    for (int st = 0; st < 4; ++st) {                                             \
        f32x4 z = (f32x4){0.f, 0.f, 0.f, 0.f};                                   \
        z = mfma16(KF[st * 2 + 0], Q0, z);                                       \
        z = mfma16(KF[st * 2 + 1], Q1, z);                                       \
        sa[st] = z;                                                              \
    }                                                                            \
    __builtin_amdgcn_s_setprio(0);                                               \
    if (MASKB) {                                                                 \
        _Pragma("unroll")                                                        \
        for (int st = 0; st < 4; ++st)                                           \
            _Pragma("unroll")                                                    \
            for (int r = 0; r < 4; ++r)                                          \
                if (st * 16 + r > dthr) sa[st][r] = -INFINITY;                   \
    }                                                                            \
    _Pragma("unroll")                                                            \
    for (int st = 0; st < 4; ++st) {                                             \
        const float e0 = exp2f(sa[st][0] - M0);                                  \
        const float e1 = exp2f(sa[st][1] - M0);                                  \
        const float e2 = exp2f(sa[st][2] - M0);                                  \
        const float e3 = exp2f(sa[st][3] - M0);                                  \
        uint2 pkv;                                                               \
        asm("v_cvt_pk_bf16_f32 %0, %1, %2" : "=v"(pkv.x) : "v"(e0), "v"(e1));    \
        asm("v_cvt_pk_bf16_f32 %0, %1, %2" : "=v"(pkv.y) : "v"(e2), "v"(e3));    \
        *(uint2*)PW[st] = pkv;                                                   \
    }                                                                            \
} while (0)

// P read + denominator + PV MFMAs, using pre-loaded V fragments
#define PVU(VF, OV, LA, PR) do {                                                 \
    bf16x8 pf0 = *(const bf16x8*)PR[0];                                          \
    bf16x8 pf1 = *(const bf16x8*)PR[1];                                          \
    __builtin_amdgcn_s_setprio(1);                                               \
    LA = mfma16(pf0, ones8, LA);                                                 \
    LA = mfma16(pf1, ones8, LA);                                                 \
    _Pragma("unroll")                                                            \
    for (int dt = 0; dt < 4; ++dt)                                               \
        OV[dt] = mfma16(pf0, VF[dt * 2 + 0], OV[dt]);                            \
    _Pragma("unroll")                                                            \
    for (int dt = 0; dt < 4; ++dt)                                               \
        OV[dt] = mfma16(pf1, VF[dt * 2 + 1], OV[dt]);                            \
    __builtin_amdgcn_s_setprio(0);                                               \
} while (0)

    STAGE();  // first event's K/V
    for (int sb = parity; sb < nsb; sb += 2) {
        const bool loact = (sb <= lo);
        asm volatile("s_waitcnt vmcnt(0)" ::: "memory");
        FENCE(); __builtin_amdgcn_s_barrier(); FENCE();
        bf16x8 kf[8];
#pragma unroll
        for (int i = 0; i < 8; ++i) kf[i] = *(const bf16x8*)(Ks + ka[i]);
        QKSM(kf, qh0, qh1, (sb == hi), pwh);
        if (loact) QKSM(kf, ql0, ql1, (sb == lo), pwl);
        bf16x8 vf[8];
#pragma unroll
        for (int i = 0; i < 8; ++i) vf[i] = *(const bf16x8*)(Vs + ka[i]);
        asm volatile("s_waitcnt lgkmcnt(0)" ::: "memory");
        FENCE(); __builtin_amdgcn_s_barrier(); FENCE();  // all waves done with K/V LDS
        if (sb + 2 < nsb) STAGE();                        // overlaps PV below
        PVU(vf, oh, lh, prh);
        if (loact) PVU(vf, ol, ll, prl);
    }

#undef PVU
#undef QKSM
#undef STAGE

    // ---- write partials (bf16 O, fp32 l); additive across parities ----
    const size_t prow = ((size_t)parity * 24 + bh) * TSEQ;
    {
#pragma unroll
        for (int r = 0; r < 4; ++r) {
            const size_t base = (prow + q0h + lg * 4 + r) * DH;
#pragma unroll
            for (int dt = 0; dt < 4; ++dt)
                opart[base + dt * 16 + l15] = __float2bfloat16(oh[dt][r]);
        }
        if (l15 == 0) {
#pragma unroll
            for (int r = 0; r < 4; ++r) lpart[prow + q0h + lg * 4 + r] = lh[r];
        }
    }
    {
#pragma unroll
        for (int r = 0; r < 4; ++r) {
            const size_t base = (prow + q0l + lg * 4 + r) * DH;
#pragma unroll
            for (int dt = 0; dt < 4; ++dt)
                opart[base + dt * 16 + l15] = __float2bfloat16(ol[dt][r]);
        }
        if (l15 == 0) {
#pragma unroll
            for (int r = 0; r < 4; ++r) lpart[prow + q0l + lg * 4 + r] = ll[r];
        }
    }
}

// ---------- combine: ab = (O0 + O1) / (l0 + l1), bf16 ----------
__global__ __launch_bounds__(256) void comb_k(const __hip_bfloat16* __restrict__ opart,
                                              const float* __restrict__ lpart,
                                              __hip_bfloat16* __restrict__ ab) {
    const int idx = blockIdx.x * 256 + threadIdx.x;
    const int row = idx >> 3;                // bh*4096 + qrow
    const int d0 = (idx & 7) * 8;
    const int bh = row >> 12, qrow = row & 4095;
    const int b_ = bh / NH, h = bh % NH;
    bf16x8 a0 = *(const bf16x8*)(opart + (size_t)row * DH + d0);
    bf16x8 a1 = *(const bf16x8*)(opart + ((size_t)NROWS + row) * DH + d0);
    const float linv = 1.0f / (lpart[row] + lpart[NROWS + row]);
    union { unsigned short u[8]; uint4 v; } o;
#pragma unroll
    for (int j = 0; j < 8; ++j) {
        const float v0 = __uint_as_float(((unsigned)(unsigned short)a0[j]) << 16);
        const float v1 = __uint_as_float(((unsigned)(unsigned short)a1[j]) << 16);
        __hip_bfloat16 hb = __float2bfloat16((v0 + v1) * linv);
        o.u[j] = *(unsigned short*)&hb;
    }
    *(uint4*)(ab + ((size_t)(b_ * TSEQ + qrow)) * EMB + h * DH + d0) = o.v;
}

extern "C" void kernel_launch(void* const* d_in, const int* in_sizes, int n_in,
                              void* d_out, int out_size, void* d_ws, size_t ws_size,
                              hipStream_t stream) {
    (void)in_sizes; (void)n_in; (void)out_size; (void)ws_size;
    const float* x  = (const float*)d_in[0];
    const float* wq = (const float*)d_in[1];
    const float* bq = (const float*)d_in[2];
    const float* wk = (const float*)d_in[3];
    const float* bk = (const float*)d_in[4];
    const float* wv = (const float*)d_in[5];
    const float* bv = (const float*)d_in[6];
    const float* wo = (const float*)d_in[7];
    const float* bo = (const float*)d_in[8];
    float* out = (float*)d_out;

    char* ws = (char*)d_ws;
    size_t off = 0;
    auto alloc = [&](size_t bytes) {
        char* p = ws + off;
        off += (bytes + 255) & ~(size_t)255;
        return p;
    };
    __hip_bfloat16* xb   = (__hip_bfloat16*)alloc((size_t)BT * EMB * 2);
    __hip_bfloat16* qbf  = (__hip_bfloat16*)alloc((size_t)BT * EMB * 2);
    __hip_bfloat16* kbf  = (__hip_bfloat16*)alloc((size_t)BT * EMB * 2);
    __hip_bfloat16* vtb  = (__hip_bfloat16*)alloc((size_t)BT * EMB * 2);
    __hip_bfloat16* abf  = (__hip_bfloat16*)alloc((size_t)BT * EMB * 2);
    __hip_bfloat16* wqT  = (__hip_bfloat16*)alloc((size_t)EMB * EMB * 2);
    __hip_bfloat16* wkT  = (__hip_bfloat16*)alloc((size_t)EMB * EMB * 2);
    __hip_bfloat16* wvT  = (__hip_bfloat16*)alloc((size_t)EMB * EMB * 2);
    __hip_bfloat16* woT  = (__hip_bfloat16*)alloc((size_t)EMB * EMB * 2);
    __hip_bfloat16* opart = (__hip_bfloat16*)alloc((size_t)2 * NROWS * DH * 2);
    float*          lpart = (float*)alloc((size_t)2 * NROWS * 4);

    conv_all_k<<<6144 + 2304, 256, 0, stream>>>(x, xb, wq, wk, wv, wo, wqT, wkT, wvT, woT);
    qkv_k<<<dim3(64, 6, 3), 256, 0, stream>>>(xb, wqT, wkT, wvT, bq, bk, bv, qbf, kbf, vtb);
    attn_k<<<1536, 256, 0, stream>>>(qbf, kbf, vtb, opart, lpart);
    comb_k<<<NROWS * 8 / 256, 256, 0, stream>>>(opart, lpart, abf);
    oproj64_k<<<dim3(128, 6), 256, 0, stream>>>(abf, woT, bo, out);
}